// Round 7
// baseline (896.178 us; speedup 1.0000x reference)
//
#include <hip/hip_runtime.h>

#define NN 100000
#define EE 1600000
#define HH 128
#define BB 8192
#define SCAN_NBLK ((NN + 1023) / 1024)   // 98

// ---------------- CSR build ----------------

__global__ void hist_kernel(const int* __restrict__ dst, int* __restrict__ hist) {
    int e = blockIdx.x * blockDim.x + threadIdx.x;
    if (e < EE) atomicAdd(&hist[dst[e]], 1);
}

__global__ void dinv_kernel(const int* __restrict__ hist, float* __restrict__ dinv) {
    int i = blockIdx.x * blockDim.x + threadIdx.x;
    if (i < NN) dinv[i] = rsqrtf((float)hist[i] + 1.0f);  // +1 self loop; deg>=1 always
}

__global__ __launch_bounds__(1024) void scan_partial_kernel(const int* __restrict__ hist,
        int* __restrict__ bsum) {
    __shared__ int red[1024];
    int i = blockIdx.x * 1024 + threadIdx.x;
    int v = (i < NN) ? hist[i] : 0;
    red[threadIdx.x] = v;
    __syncthreads();
    for (int d = 512; d > 0; d >>= 1) {
        if (threadIdx.x < d) red[threadIdx.x] += red[threadIdx.x + d];
        __syncthreads();
    }
    if (threadIdx.x == 0) bsum[blockIdx.x] = red[0];
}

__global__ void scan_sums_kernel(const int* __restrict__ bsum, int* __restrict__ bbase) {
    int acc = 0;
    for (int b = 0; b < SCAN_NBLK; ++b) { bbase[b] = acc; acc += bsum[b]; }
    bbase[SCAN_NBLK] = acc;
}

__global__ __launch_bounds__(1024) void scan_offs_kernel(const int* __restrict__ hist,
        const int* __restrict__ bbase, int* __restrict__ offs, int* __restrict__ cursor) {
    __shared__ int sc[1024];
    int i = blockIdx.x * 1024 + threadIdx.x;
    int v = (i < NN) ? hist[i] : 0;
    sc[threadIdx.x] = v;
    __syncthreads();
    for (int d = 1; d < 1024; d <<= 1) {
        int t = (threadIdx.x >= d) ? sc[threadIdx.x - d] : 0;
        __syncthreads();
        sc[threadIdx.x] += t;
        __syncthreads();
    }
    if (i < NN) {
        int excl = bbase[blockIdx.x] + sc[threadIdx.x] - v;
        offs[i] = excl;
        cursor[i] = excl;
        if (i == NN - 1) offs[NN] = excl + v;
    }
}

__global__ void fill_kernel(const int* __restrict__ src, const int* __restrict__ dst,
        const float* __restrict__ dinv, int* __restrict__ cursor,
        int* __restrict__ esrc, float* __restrict__ enorm) {
    int e = blockIdx.x * blockDim.x + threadIdx.x;
    if (e >= EE) return;
    int s = src[e], d = dst[e];
    int p = atomicAdd(&cursor[d], 1);
    esrc[p] = s;
    enorm[p] = dinv[s] * dinv[d];
}

// ---------------- fp32 GEMM v2 [M,128] x [128,128] ----------------
// 256 threads, tile 128 rows x 128 cols, thread = 8 rows x 8 cols.
// v1 was LDS-throughput-bound (~96 B per wave-FMA vs 128 B/cyc budget, 28 TF).
// v2: As staged as [k4][row][float4] with strided row ownership
// (row = trowg + 16*r): a-reads are 4 distinct addrs / 4 distinct banks with
// 16-way broadcast (conflict-free, tiny distinct-byte volume). 8x8 register
// tile -> ~10 distinct LDS bytes per wave-FMA -> FMA-bound (~21 us roofline).

__global__ __launch_bounds__(256) void gemm128(const float* __restrict__ A,
        const float* __restrict__ W, const float* __restrict__ bias,
        float* __restrict__ C, int M, int relu) {
    __shared__ float4 As4[16 * 128];  // 32 KB: [k4][row] -> 4 k-floats
    __shared__ float4 Ws4[64 * 32];   // 32 KB: [k][c4]  -> 4 cols
    const int tid = threadIdx.x;
    const int row0 = blockIdx.x * 128;
    const int tcol8 = tid & 15;       // cols tcol8*8 .. +7
    const int trowg = tid >> 4;       // rows trowg + 16*r, r=0..7

    float acc[8][8];
#pragma unroll
    for (int r = 0; r < 8; ++r)
#pragma unroll
        for (int c = 0; c < 8; ++c) acc[r][c] = 0.f;

    const float4* A4 = (const float4*)A;
    const float4* W4 = (const float4*)W;

    for (int kc = 0; kc < 128; kc += 64) {
        __syncthreads();  // protect LDS from previous chunk's readers
        // stage A chunk: 128 rows x 64 k = 2048 float4, 8 per thread
#pragma unroll
        for (int i = 0; i < 8; ++i) {
            int p = tid + 256 * i;
            int row = p >> 4, k4 = p & 15;
            int gr = row0 + row;
            float4 v = make_float4(0.f, 0.f, 0.f, 0.f);
            if (gr < M) v = A4[(size_t)gr * 32 + (kc >> 2) + k4];
            As4[k4 * 128 + row] = v;
        }
        // stage W chunk: rows kc..kc+63 x 128 cols = 2048 float4
#pragma unroll
        for (int i = 0; i < 8; ++i) {
            int p = tid + 256 * i;
            Ws4[p] = W4[(size_t)kc * 32 + p];
        }
        __syncthreads();

#pragma unroll
        for (int k4 = 0; k4 < 16; ++k4) {
            float4 a[8];
#pragma unroll
            for (int r = 0; r < 8; ++r)
                a[r] = As4[k4 * 128 + trowg + 16 * r];
#pragma unroll
            for (int kk = 0; kk < 4; ++kk) {
                int k = k4 * 4 + kk;
                float4 w0 = Ws4[k * 32 + tcol8 * 2];
                float4 w1 = Ws4[k * 32 + tcol8 * 2 + 1];
#pragma unroll
                for (int r = 0; r < 8; ++r) {
                    float av = (kk == 0) ? a[r].x : (kk == 1) ? a[r].y
                             : (kk == 2) ? a[r].z : a[r].w;
                    acc[r][0] += av * w0.x; acc[r][1] += av * w0.y;
                    acc[r][2] += av * w0.z; acc[r][3] += av * w0.w;
                    acc[r][4] += av * w1.x; acc[r][5] += av * w1.y;
                    acc[r][6] += av * w1.z; acc[r][7] += av * w1.w;
                }
            }
        }
    }

    float bv[8];
#pragma unroll
    for (int c = 0; c < 8; ++c) bv[c] = 0.f;
    if (bias) {
        float4 b0 = ((const float4*)bias)[tcol8 * 2];
        float4 b1 = ((const float4*)bias)[tcol8 * 2 + 1];
        bv[0] = b0.x; bv[1] = b0.y; bv[2] = b0.z; bv[3] = b0.w;
        bv[4] = b1.x; bv[5] = b1.y; bv[6] = b1.z; bv[7] = b1.w;
    }
    float4* C4 = (float4*)C;
#pragma unroll
    for (int r = 0; r < 8; ++r) {
        int gr = row0 + trowg + 16 * r;
        if (gr < M) {
            float o[8];
#pragma unroll
            for (int c = 0; c < 8; ++c) {
                float v = acc[r][c] + bv[c];
                o[c] = relu ? fmaxf(v, 0.f) : v;
            }
            C4[(size_t)gr * 32 + tcol8 * 2]     = make_float4(o[0], o[1], o[2], o[3]);
            C4[(size_t)gr * 32 + tcol8 * 2 + 1] = make_float4(o[4], o[5], o[6], o[7]);
        }
    }
}

// ---------------- aggregation v2 ----------------
// out[i] = sum_in-edges t[src]*norm + t[i]*dinv[i]^2 + b.
// One wave per node; float4 per lane, half-wave per edge (2 edges per pass),
// 4-deep unroll -> 8 edges (4 KB) in flight. v1 was latency-bound
// (VALUBusy 19%, 3.45 TB/s fetch path): double bytes/inst + MLP.

__global__ __launch_bounds__(256) void agg_kernel(const float* __restrict__ t,
        float* __restrict__ out, const int* __restrict__ offs,
        const int* __restrict__ esrc, const float* __restrict__ enorm,
        const float* __restrict__ dinv, const float* __restrict__ bias, int relu) {
    const int wave = threadIdx.x >> 6;
    const int lane = threadIdx.x & 63;
    const int node = blockIdx.x * 4 + wave;
    if (node >= NN) return;
    const int half = lane >> 5;       // 0: even edges, 1: odd edges
    const int hl = lane & 31;         // float4 slot within the 128-f row

    const float4* t4 = (const float4*)t;
    float ax = 0.f, ay = 0.f, az = 0.f, aw = 0.f;

    if (half == 0) {  // self-loop term on half 0 only
        float di = dinv[node];
        float s = di * di;
        float4 sv = t4[(size_t)node * 32 + hl];
        ax = sv.x * s; ay = sv.y * s; az = sv.z * s; aw = sv.w * s;
    }

    int e = offs[node];
    const int e1 = offs[node + 1];
    for (; e + 8 <= e1; e += 8) {
        int i0 = e + half,     i1 = e + 2 + half;
        int i2 = e + 4 + half, i3 = e + 6 + half;
        int s0 = esrc[i0], s1 = esrc[i1], s2 = esrc[i2], s3 = esrc[i3];
        float n0 = enorm[i0], n1 = enorm[i1], n2 = enorm[i2], n3 = enorm[i3];
        float4 v0 = t4[(size_t)s0 * 32 + hl];
        float4 v1 = t4[(size_t)s1 * 32 + hl];
        float4 v2 = t4[(size_t)s2 * 32 + hl];
        float4 v3 = t4[(size_t)s3 * 32 + hl];
        ax += v0.x * n0; ay += v0.y * n0; az += v0.z * n0; aw += v0.w * n0;
        ax += v1.x * n1; ay += v1.y * n1; az += v1.z * n1; aw += v1.w * n1;
        ax += v2.x * n2; ay += v2.y * n2; az += v2.z * n2; aw += v2.w * n2;
        ax += v3.x * n3; ay += v3.y * n3; az += v3.z * n3; aw += v3.w * n3;
    }
    for (; e + 2 <= e1; e += 2) {
        int ee = e + half;
        int s = esrc[ee];
        float nm = enorm[ee];
        float4 v = t4[(size_t)s * 32 + hl];
        ax += v.x * nm; ay += v.y * nm; az += v.z * nm; aw += v.w * nm;
    }
    if (e < e1 && half == 0) {  // final odd edge
        int s = esrc[e];
        float nm = enorm[e];
        float4 v = t4[(size_t)s * 32 + hl];
        ax += v.x * nm; ay += v.y * nm; az += v.z * nm; aw += v.w * nm;
    }

    // combine the two half-wave partial sums (lane <-> lane^32)
    ax += __shfl_xor(ax, 32); ay += __shfl_xor(ay, 32);
    az += __shfl_xor(az, 32); aw += __shfl_xor(aw, 32);

    if (half == 0) {
        if (bias) {
            float4 b = ((const float4*)bias)[hl];
            ax += b.x; ay += b.y; az += b.z; aw += b.w;
        }
        if (relu) {
            ax = fmaxf(ax, 0.f); ay = fmaxf(ay, 0.f);
            az = fmaxf(az, 0.f); aw = fmaxf(aw, 0.f);
        }
        ((float4*)out)[(size_t)node * 32 + hl] = make_float4(ax, ay, az, aw);
    }
}

// ---------------- link head ----------------

__global__ __launch_bounds__(256) void link_kernel(const float* __restrict__ h,
        const int* __restrict__ roots, float* __restrict__ linkb) {
    const int wave = threadIdx.x >> 6;
    const int lane = threadIdx.x & 63;
    const int b = blockIdx.x * 4 + wave;
    if (b >= BB) return;
    const int f = lane * 2;
    int r0 = roots[b * 2], r1 = roots[b * 2 + 1];
    float2 u = *(const float2*)&h[(size_t)r0 * HH + f];
    float2 v = *(const float2*)&h[(size_t)r1 * HH + f];
    *(float2*)&linkb[(size_t)b * HH + f] = make_float2(u.x * v.x, u.y * v.y);
}

__global__ __launch_bounds__(256) void logits_kernel(const float* __restrict__ g,
        const float* __restrict__ P2, const float* __restrict__ pb2,
        float* __restrict__ out) {
    const int wave = threadIdx.x >> 6;
    const int lane = threadIdx.x & 63;
    const int b = blockIdx.x * 4 + wave;
    if (b >= BB) return;
    const int f = lane * 2;
    float2 gv = *(const float2*)&g[(size_t)b * HH + f];
    float2 pv = *(const float2*)&P2[f];
    float s = gv.x * pv.x + gv.y * pv.y;
    for (int off = 32; off > 0; off >>= 1) s += __shfl_down(s, off);
    if (lane == 0) out[b] = s + pb2[0];
}

// ---------------- launcher ----------------

extern "C" void kernel_launch(void* const* d_in, const int* in_sizes, int n_in,
                              void* d_out, int out_size, void* d_ws, size_t ws_size,
                              hipStream_t stream) {
    const float* x   = (const float*)d_in[0];
    const int*   ei  = (const int*)d_in[1];
    const int* roots = (const int*)d_in[2];
    const float* W1  = (const float*)d_in[3];
    const float* b1  = (const float*)d_in[4];
    const float* W2  = (const float*)d_in[5];
    const float* b2  = (const float*)d_in[6];
    const float* W3  = (const float*)d_in[7];
    const float* b3  = (const float*)d_in[8];
    const float* P1  = (const float*)d_in[9];
    const float* pb1 = (const float*)d_in[10];
    const float* P2  = (const float*)d_in[11];
    const float* pb2 = (const float*)d_in[12];
    float* out = (float*)d_out;
    (void)in_sizes; (void)n_in; (void)out_size; (void)ws_size;

    char* ws = (char*)d_ws;
    size_t woff = 0;
    auto alloc = [&](size_t bytes) {
        void* p = ws + woff;
        woff += (bytes + 255) & ~(size_t)255;
        return p;
    };
    int*   hist   = (int*)  alloc((size_t)NN * 4);
    float* dinv   = (float*)alloc((size_t)NN * 4);
    int*   offs   = (int*)  alloc((size_t)(NN + 1) * 4);
    int*   cursor = (int*)  alloc((size_t)NN * 4);
    int*   bsum   = (int*)  alloc((size_t)(SCAN_NBLK + 1) * 4);
    int*   bbase  = (int*)  alloc((size_t)(SCAN_NBLK + 1) * 4);
    int*   esrc   = (int*)  alloc((size_t)EE * 4);
    float* enorm  = (float*)alloc((size_t)EE * 4);
    float* bufA   = (float*)alloc((size_t)NN * HH * 4);
    float* bufB   = (float*)alloc((size_t)NN * HH * 4);
    float* linkb  = (float*)alloc((size_t)BB * HH * 4);
    float* gout   = (float*)alloc((size_t)BB * HH * 4);

    const int* e_src = ei;        // edge_index[0]
    const int* e_dst = ei + EE;   // edge_index[1]

    hipMemsetAsync(hist, 0, (size_t)NN * 4, stream);
    hist_kernel<<<(EE + 255) / 256, 256, 0, stream>>>(e_dst, hist);
    dinv_kernel<<<(NN + 255) / 256, 256, 0, stream>>>(hist, dinv);
    scan_partial_kernel<<<SCAN_NBLK, 1024, 0, stream>>>(hist, bsum);
    scan_sums_kernel<<<1, 1, 0, stream>>>(bsum, bbase);
    scan_offs_kernel<<<SCAN_NBLK, 1024, 0, stream>>>(hist, bbase, offs, cursor);
    fill_kernel<<<(EE + 255) / 256, 256, 0, stream>>>(e_src, e_dst, dinv, cursor, esrc, enorm);

    // layer 1: t = x@W1 ; h1 = relu(agg(t) + b1)
    gemm128<<<(NN + 127) / 128, 256, 0, stream>>>(x, W1, nullptr, bufA, NN, 0);
    agg_kernel<<<(NN + 3) / 4, 256, 0, stream>>>(bufA, bufB, offs, esrc, enorm, dinv, b1, 1);
    // layer 2
    gemm128<<<(NN + 127) / 128, 256, 0, stream>>>(bufB, W2, nullptr, bufA, NN, 0);
    agg_kernel<<<(NN + 3) / 4, 256, 0, stream>>>(bufA, bufB, offs, esrc, enorm, dinv, b2, 1);
    // layer 3 (no relu)
    gemm128<<<(NN + 127) / 128, 256, 0, stream>>>(bufB, W3, nullptr, bufA, NN, 0);
    agg_kernel<<<(NN + 3) / 4, 256, 0, stream>>>(bufA, bufB, offs, esrc, enorm, dinv, b3, 0);

    // head
    link_kernel<<<(BB + 3) / 4, 256, 0, stream>>>(bufB, roots, linkb);
    gemm128<<<(BB + 127) / 128, 256, 0, stream>>>(linkb, P1, pb1, gout, BB, 1);
    logits_kernel<<<(BB + 3) / 4, 256, 0, stream>>>(gout, P2, pb2, out);
}

// Round 10
// 780.664 us; speedup vs baseline: 1.1480x; 1.1480x over previous
//
#include <hip/hip_runtime.h>

#define NN 100000
#define EE 1600000
#define HH 128
#define BB 8192
#define SCAN_NBLK ((NN + 1023) / 1024)   // 98
#define LDA 136                          // padded bf16 row: 2-way-free LDS reads

typedef __attribute__((ext_vector_type(8))) short bf16x8;
typedef __attribute__((ext_vector_type(4))) float f32x4;

// split fp32 into bf16 hi + bf16 lo (truncation; |lo|<=2^-8|a|, dropped
// al*wl term <= 2^-16 relative)
__device__ __forceinline__ void split2(float a, ushort& hi, ushort& lo) {
    unsigned u = __float_as_uint(a);
    hi = (ushort)(u >> 16);
    float hf = __uint_as_float(u & 0xFFFF0000u);
    float l = a - hf;
    lo = (ushort)(__float_as_uint(l) >> 16);
}

// ---------------- CSR build ----------------

__global__ void hist_kernel(const int* __restrict__ dst, int* __restrict__ hist) {
    int e = blockIdx.x * blockDim.x + threadIdx.x;
    if (e < EE) atomicAdd(&hist[dst[e]], 1);
}

__global__ void dinv_kernel(const int* __restrict__ hist, float* __restrict__ dinv) {
    int i = blockIdx.x * blockDim.x + threadIdx.x;
    if (i < NN) dinv[i] = rsqrtf((float)hist[i] + 1.0f);
}

__global__ __launch_bounds__(1024) void scan_partial_kernel(const int* __restrict__ hist,
        int* __restrict__ bsum) {
    __shared__ int red[1024];
    int i = blockIdx.x * 1024 + threadIdx.x;
    int v = (i < NN) ? hist[i] : 0;
    red[threadIdx.x] = v;
    __syncthreads();
    for (int d = 512; d > 0; d >>= 1) {
        if (threadIdx.x < d) red[threadIdx.x] += red[threadIdx.x + d];
        __syncthreads();
    }
    if (threadIdx.x == 0) bsum[blockIdx.x] = red[0];
}

__global__ void scan_sums_kernel(const int* __restrict__ bsum, int* __restrict__ bbase) {
    int acc = 0;
    for (int b = 0; b < SCAN_NBLK; ++b) { bbase[b] = acc; acc += bsum[b]; }
    bbase[SCAN_NBLK] = acc;
}

__global__ __launch_bounds__(1024) void scan_offs_kernel(const int* __restrict__ hist,
        const int* __restrict__ bbase, int* __restrict__ offs, int* __restrict__ cursor) {
    __shared__ int sc[1024];
    int i = blockIdx.x * 1024 + threadIdx.x;
    int v = (i < NN) ? hist[i] : 0;
    sc[threadIdx.x] = v;
    __syncthreads();
    for (int d = 1; d < 1024; d <<= 1) {
        int t = (threadIdx.x >= d) ? sc[threadIdx.x - d] : 0;
        __syncthreads();
        sc[threadIdx.x] += t;
        __syncthreads();
    }
    if (i < NN) {
        int excl = bbase[blockIdx.x] + sc[threadIdx.x] - v;
        offs[i] = excl;
        cursor[i] = excl;
        if (i == NN - 1) offs[NN] = excl + v;
    }
}

__global__ void fill_kernel(const int* __restrict__ src, const int* __restrict__ dst,
        const float* __restrict__ dinv, int* __restrict__ cursor,
        int* __restrict__ esrc, float* __restrict__ enorm) {
    int e = blockIdx.x * blockDim.x + threadIdx.x;
    if (e >= EE) return;
    int s = src[e], d = dst[e];
    int p = atomicAdd(&cursor[d], 1);
    esrc[p] = s;
    enorm[p] = dinv[s] * dinv[d];
}

// ---------------- W pre-split into MFMA-fragment-ordered bf16 ----------------
// entry e = kind*2048 + k0*512 + ct*64 + lane; each entry = 8 bf16 (one b-frag
// register quad): B[k0*32+(lane>>4)*8+j][ct*16+(lane&15)], j=0..7.

__global__ __launch_bounds__(256) void wsplit_kernel(const float* __restrict__ W,
        short* __restrict__ Wf) {
    int e = blockIdx.x * 256 + threadIdx.x;   // 4096 entries
    int kind = e >> 11;
    int k0 = (e >> 9) & 3;
    int ct = (e >> 6) & 7;
    int l = e & 63;
    int kb = k0 * 32 + (l >> 4) * 8;
    int c = ct * 16 + (l & 15);
    short v[8];
#pragma unroll
    for (int j = 0; j < 8; ++j) {
        float w = W[(size_t)(kb + j) * HH + c];
        ushort hi, lo;
        split2(w, hi, lo);
        v[j] = (short)(kind ? lo : hi);
    }
    bf16x8 pack;
#pragma unroll
    for (int j = 0; j < 8; ++j) pack[j] = v[j];
    *(bf16x8*)(Wf + (size_t)e * 8) = pack;
}

// ---------------- MFMA GEMM [M,128] x [128,128] via bf16 split ----------------
// C = Ah@Wh + Ah@Wl + Al@Wh. Block: 128 rows x 128 cols, 4 waves; wave = 32
// rows x 128 cols = 2x8 16x16 tiles. A hi/lo staged to LDS [128][136] bf16
// (pad -> ds_read_b128 exactly 2-way = free). W-frags read coalesced from the
// 64 KB L2-resident pre-split array. Fragment layouts per m89/m91 (verified):
// A: row=lane&15,k=(lane>>4)*8+j; B: col=lane&15; C/D: col=lane&15,
// row=(lane>>4)*4+reg.

__global__ __launch_bounds__(256) void gemm_mfma(const float* __restrict__ A,
        const short* __restrict__ Wf, const float* __restrict__ bias,
        float* __restrict__ C, int M, int relu) {
    __shared__ short Ah[128 * LDA];
    __shared__ short Al[128 * LDA];
    const int tid = threadIdx.x;
    const int row0 = blockIdx.x * 128;

    // stage + split A tile: 128 rows x 32 float4
    const float4* A4 = (const float4*)A;
#pragma unroll
    for (int i = 0; i < 16; ++i) {
        int p = i * 256 + tid;
        int row = p >> 5, k4 = p & 31;
        int gr = row0 + row;
        float4 v = make_float4(0.f, 0.f, 0.f, 0.f);
        if (gr < M) v = A4[(size_t)gr * 32 + k4];
        ushort h0, l0, h1, l1, h2, l2, h3, l3;
        split2(v.x, h0, l0); split2(v.y, h1, l1);
        split2(v.z, h2, l2); split2(v.w, h3, l3);
        *(short4*)&Ah[row * LDA + k4 * 4] =
            make_short4((short)h0, (short)h1, (short)h2, (short)h3);
        *(short4*)&Al[row * LDA + k4 * 4] =
            make_short4((short)l0, (short)l1, (short)l2, (short)l3);
    }
    __syncthreads();

    const int lane = tid & 63;
    const int wave = tid >> 6;
    const int wr0 = wave * 32;
    const int arow = lane & 15;
    const int koff = (lane >> 4) * 8;

    f32x4 acc[2][8];
#pragma unroll
    for (int rt = 0; rt < 2; ++rt)
#pragma unroll
        for (int ct = 0; ct < 8; ++ct)
#pragma unroll
            for (int m = 0; m < 4; ++m) acc[rt][ct][m] = 0.f;

    for (int k0 = 0; k0 < 4; ++k0) {
        bf16x8 wh[8], wl[8];
#pragma unroll
        for (int ct = 0; ct < 8; ++ct) {
            wh[ct] = *(const bf16x8*)(Wf + ((size_t)(k0 * 8 + ct) * 64 + lane) * 8);
            wl[ct] = *(const bf16x8*)(Wf + ((size_t)(2048 + k0 * 512 + ct * 64 + lane)) * 8);
        }
        bf16x8 ah[2], al[2];
#pragma unroll
        for (int rt = 0; rt < 2; ++rt) {
            int r = wr0 + rt * 16 + arow;
            ah[rt] = *(const bf16x8*)&Ah[r * LDA + k0 * 32 + koff];
            al[rt] = *(const bf16x8*)&Al[r * LDA + k0 * 32 + koff];
        }
#pragma unroll
        for (int rt = 0; rt < 2; ++rt)
#pragma unroll
            for (int ct = 0; ct < 8; ++ct) {
                acc[rt][ct] = __builtin_amdgcn_mfma_f32_16x16x32_bf16(
                    ah[rt], wh[ct], acc[rt][ct], 0, 0, 0);
                acc[rt][ct] = __builtin_amdgcn_mfma_f32_16x16x32_bf16(
                    ah[rt], wl[ct], acc[rt][ct], 0, 0, 0);
                acc[rt][ct] = __builtin_amdgcn_mfma_f32_16x16x32_bf16(
                    al[rt], wh[ct], acc[rt][ct], 0, 0, 0);
            }
    }

    const int ccol = lane & 15;
    const int crow = (lane >> 4) * 4;
#pragma unroll
    for (int ct = 0; ct < 8; ++ct) {
        float bv = bias ? bias[ct * 16 + ccol] : 0.f;
#pragma unroll
        for (int rt = 0; rt < 2; ++rt) {
#pragma unroll
            for (int m = 0; m < 4; ++m) {
                int gr = row0 + wr0 + rt * 16 + crow + m;
                if (gr < M) {
                    float v = acc[rt][ct][m] + bv;
                    if (relu) v = fmaxf(v, 0.f);
                    C[(size_t)gr * HH + ct * 16 + ccol] = v;
                }
            }
        }
    }
}

// ---------------- aggregation (at its ~3.9 TB/s random-gather wall) ----------------

__global__ __launch_bounds__(256) void agg_kernel(const float* __restrict__ t,
        float* __restrict__ out, const int* __restrict__ offs,
        const int* __restrict__ esrc, const float* __restrict__ enorm,
        const float* __restrict__ dinv, const float* __restrict__ bias, int relu) {
    const int wave = threadIdx.x >> 6;
    const int lane = threadIdx.x & 63;
    const int node = blockIdx.x * 4 + wave;
    if (node >= NN) return;
    const int half = lane >> 5;
    const int hl = lane & 31;

    const float4* t4 = (const float4*)t;
    float ax = 0.f, ay = 0.f, az = 0.f, aw = 0.f;

    if (half == 0) {
        float di = dinv[node];
        float s = di * di;
        float4 sv = t4[(size_t)node * 32 + hl];
        ax = sv.x * s; ay = sv.y * s; az = sv.z * s; aw = sv.w * s;
    }

    int e = offs[node];
    const int e1 = offs[node + 1];
    for (; e + 8 <= e1; e += 8) {
        int i0 = e + half, i1 = e + 2 + half, i2 = e + 4 + half, i3 = e + 6 + half;
        int s0 = esrc[i0], s1 = esrc[i1], s2 = esrc[i2], s3 = esrc[i3];
        float n0 = enorm[i0], n1 = enorm[i1], n2 = enorm[i2], n3 = enorm[i3];
        float4 v0 = t4[(size_t)s0 * 32 + hl];
        float4 v1 = t4[(size_t)s1 * 32 + hl];
        float4 v2 = t4[(size_t)s2 * 32 + hl];
        float4 v3 = t4[(size_t)s3 * 32 + hl];
        ax += v0.x * n0; ay += v0.y * n0; az += v0.z * n0; aw += v0.w * n0;
        ax += v1.x * n1; ay += v1.y * n1; az += v1.z * n1; aw += v1.w * n1;
        ax += v2.x * n2; ay += v2.y * n2; az += v2.z * n2; aw += v2.w * n2;
        ax += v3.x * n3; ay += v3.y * n3; az += v3.z * n3; aw += v3.w * n3;
    }
    for (; e + 2 <= e1; e += 2) {
        int ee = e + half;
        int s = esrc[ee];
        float nm = enorm[ee];
        float4 v = t4[(size_t)s * 32 + hl];
        ax += v.x * nm; ay += v.y * nm; az += v.z * nm; aw += v.w * nm;
    }
    if (e < e1 && half == 0) {
        int s = esrc[e];
        float nm = enorm[e];
        float4 v = t4[(size_t)s * 32 + hl];
        ax += v.x * nm; ay += v.y * nm; az += v.z * nm; aw += v.w * nm;
    }

    ax += __shfl_xor(ax, 32); ay += __shfl_xor(ay, 32);
    az += __shfl_xor(az, 32); aw += __shfl_xor(aw, 32);

    if (half == 0) {
        if (bias) {
            float4 b = ((const float4*)bias)[hl];
            ax += b.x; ay += b.y; az += b.z; aw += b.w;
        }
        if (relu) {
            ax = fmaxf(ax, 0.f); ay = fmaxf(ay, 0.f);
            az = fmaxf(az, 0.f); aw = fmaxf(aw, 0.f);
        }
        ((float4*)out)[(size_t)node * 32 + hl] = make_float4(ax, ay, az, aw);
    }
}

// ---------------- link head ----------------

__global__ __launch_bounds__(256) void link_kernel(const float* __restrict__ h,
        const int* __restrict__ roots, float* __restrict__ linkb) {
    const int wave = threadIdx.x >> 6;
    const int lane = threadIdx.x & 63;
    const int b = blockIdx.x * 4 + wave;
    if (b >= BB) return;
    const int f = lane * 2;
    int r0 = roots[b * 2], r1 = roots[b * 2 + 1];
    float2 u = *(const float2*)&h[(size_t)r0 * HH + f];
    float2 v = *(const float2*)&h[(size_t)r1 * HH + f];
    *(float2*)&linkb[(size_t)b * HH + f] = make_float2(u.x * v.x, u.y * v.y);
}

__global__ __launch_bounds__(256) void logits_kernel(const float* __restrict__ g,
        const float* __restrict__ P2, const float* __restrict__ pb2,
        float* __restrict__ out) {
    const int wave = threadIdx.x >> 6;
    const int lane = threadIdx.x & 63;
    const int b = blockIdx.x * 4 + wave;
    if (b >= BB) return;
    const int f = lane * 2;
    float2 gv = *(const float2*)&g[(size_t)b * HH + f];
    float2 pv = *(const float2*)&P2[f];
    float s = gv.x * pv.x + gv.y * pv.y;
    for (int off = 32; off > 0; off >>= 1) s += __shfl_down(s, off);
    if (lane == 0) out[b] = s + pb2[0];
}

// ---------------- launcher ----------------

extern "C" void kernel_launch(void* const* d_in, const int* in_sizes, int n_in,
                              void* d_out, int out_size, void* d_ws, size_t ws_size,
                              hipStream_t stream) {
    const float* x   = (const float*)d_in[0];
    const int*   ei  = (const int*)d_in[1];
    const int* roots = (const int*)d_in[2];
    const float* W1  = (const float*)d_in[3];
    const float* b1  = (const float*)d_in[4];
    const float* W2  = (const float*)d_in[5];
    const float* b2  = (const float*)d_in[6];
    const float* W3  = (const float*)d_in[7];
    const float* b3  = (const float*)d_in[8];
    const float* P1  = (const float*)d_in[9];
    const float* pb1 = (const float*)d_in[10];
    const float* P2  = (const float*)d_in[11];
    const float* pb2 = (const float*)d_in[12];
    float* out = (float*)d_out;
    (void)in_sizes; (void)n_in; (void)out_size; (void)ws_size;

    char* ws = (char*)d_ws;
    size_t woff = 0;
    auto alloc = [&](size_t bytes) {
        void* p = ws + woff;
        woff += (bytes + 255) & ~(size_t)255;
        return p;
    };
    int*   hist   = (int*)  alloc((size_t)NN * 4);
    float* dinv   = (float*)alloc((size_t)NN * 4);
    int*   offs   = (int*)  alloc((size_t)(NN + 1) * 4);
    int*   cursor = (int*)  alloc((size_t)NN * 4);
    int*   bsum   = (int*)  alloc((size_t)(SCAN_NBLK + 1) * 4);
    int*   bbase  = (int*)  alloc((size_t)(SCAN_NBLK + 1) * 4);
    int*   esrc   = (int*)  alloc((size_t)EE * 4);
    float* enorm  = (float*)alloc((size_t)EE * 4);
    float* bufA   = (float*)alloc((size_t)NN * HH * 4);
    float* bufB   = (float*)alloc((size_t)NN * HH * 4);
    float* linkb  = (float*)alloc((size_t)BB * HH * 4);
    float* gout   = (float*)alloc((size_t)BB * HH * 4);
    short* Wf1    = (short*)alloc((size_t)4096 * 8 * 2);
    short* Wf2    = (short*)alloc((size_t)4096 * 8 * 2);
    short* Wf3    = (short*)alloc((size_t)4096 * 8 * 2);
    short* WfP1   = (short*)alloc((size_t)4096 * 8 * 2);

    const int* e_src = ei;        // edge_index[0]
    const int* e_dst = ei + EE;   // edge_index[1]

    hipMemsetAsync(hist, 0, (size_t)NN * 4, stream);
    hist_kernel<<<(EE + 255) / 256, 256, 0, stream>>>(e_dst, hist);
    dinv_kernel<<<(NN + 255) / 256, 256, 0, stream>>>(hist, dinv);
    scan_partial_kernel<<<SCAN_NBLK, 1024, 0, stream>>>(hist, bsum);
    scan_sums_kernel<<<1, 1, 0, stream>>>(bsum, bbase);
    scan_offs_kernel<<<SCAN_NBLK, 1024, 0, stream>>>(hist, bbase, offs, cursor);
    fill_kernel<<<(EE + 255) / 256, 256, 0, stream>>>(e_src, e_dst, dinv, cursor, esrc, enorm);

    // pre-split weights into fragment-ordered bf16 hi/lo
    wsplit_kernel<<<16, 256, 0, stream>>>(W1, Wf1);
    wsplit_kernel<<<16, 256, 0, stream>>>(W2, Wf2);
    wsplit_kernel<<<16, 256, 0, stream>>>(W3, Wf3);
    wsplit_kernel<<<16, 256, 0, stream>>>(P1, WfP1);

    // layer 1
    gemm_mfma<<<(NN + 127) / 128, 256, 0, stream>>>(x, Wf1, nullptr, bufA, NN, 0);
    agg_kernel<<<(NN + 3) / 4, 256, 0, stream>>>(bufA, bufB, offs, esrc, enorm, dinv, b1, 1);
    // layer 2
    gemm_mfma<<<(NN + 127) / 128, 256, 0, stream>>>(bufB, Wf2, nullptr, bufA, NN, 0);
    agg_kernel<<<(NN + 3) / 4, 256, 0, stream>>>(bufA, bufB, offs, esrc, enorm, dinv, b2, 1);
    // layer 3 (no relu)
    gemm_mfma<<<(NN + 127) / 128, 256, 0, stream>>>(bufB, Wf3, nullptr, bufA, NN, 0);
    agg_kernel<<<(NN + 3) / 4, 256, 0, stream>>>(bufA, bufB, offs, esrc, enorm, dinv, b3, 0);

    // head
    link_kernel<<<(BB + 3) / 4, 256, 0, stream>>>(bufB, roots, linkb);
    gemm_mfma<<<(BB + 127) / 128, 256, 0, stream>>>(linkb, WfP1, pb1, gout, BB, 1);
    logits_kernel<<<(BB + 3) / 4, 256, 0, stream>>>(gout, P2, pb2, out);
}

// Round 12
// 768.445 us; speedup vs baseline: 1.1662x; 1.0159x over previous
//
#include <hip/hip_runtime.h>

#define NN 100000
#define EE 1600000
#define HH 128
#define BB 8192
#define SCAN_NBLK ((NN + 1023) / 1024)   // 98
#define LDA 136                          // padded bf16 row: 2-way-free LDS writes

typedef __attribute__((ext_vector_type(8))) short bf16x8;
typedef __attribute__((ext_vector_type(4))) float f32x4;

// split fp32 into bf16 hi + bf16 lo (truncation; dropped al*wl <= 2^-16 rel)
__device__ __forceinline__ void split2(float a, ushort& hi, ushort& lo) {
    unsigned u = __float_as_uint(a);
    hi = (ushort)(u >> 16);
    float hf = __uint_as_float(u & 0xFFFF0000u);
    float l = a - hf;
    lo = (ushort)(__float_as_uint(l) >> 16);
}

// ---------------- CSR build ----------------

__global__ void hist_kernel(const int* __restrict__ dst, int* __restrict__ hist) {
    int e = blockIdx.x * blockDim.x + threadIdx.x;
    if (e < EE) atomicAdd(&hist[dst[e]], 1);
}

__global__ void dinv_kernel(const int* __restrict__ hist, float* __restrict__ dinv) {
    int i = blockIdx.x * blockDim.x + threadIdx.x;
    if (i < NN) dinv[i] = rsqrtf((float)hist[i] + 1.0f);
}

__global__ __launch_bounds__(1024) void scan_partial_kernel(const int* __restrict__ hist,
        int* __restrict__ bsum) {
    __shared__ int red[1024];
    int i = blockIdx.x * 1024 + threadIdx.x;
    int v = (i < NN) ? hist[i] : 0;
    red[threadIdx.x] = v;
    __syncthreads();
    for (int d = 512; d > 0; d >>= 1) {
        if (threadIdx.x < d) red[threadIdx.x] += red[threadIdx.x + d];
        __syncthreads();
    }
    if (threadIdx.x == 0) bsum[blockIdx.x] = red[0];
}

// 128-thread scan of the 98 block sums (was 1 thread x 99 serial iters)
__global__ __launch_bounds__(128) void scan_sums_kernel(const int* __restrict__ bsum,
        int* __restrict__ bbase) {
    __shared__ int sc[128];
    int t = threadIdx.x;
    int v = (t < SCAN_NBLK) ? bsum[t] : 0;
    sc[t] = v;
    __syncthreads();
    for (int d = 1; d < 128; d <<= 1) {
        int u = (t >= d) ? sc[t - d] : 0;
        __syncthreads();
        sc[t] += u;
        __syncthreads();
    }
    if (t <= SCAN_NBLK) bbase[t] = sc[t] - v;   // exclusive; t==SCAN_NBLK: v=0 -> total
}

__global__ __launch_bounds__(1024) void scan_offs_kernel(const int* __restrict__ hist,
        const int* __restrict__ bbase, int* __restrict__ offs, int* __restrict__ cursor) {
    __shared__ int sc[1024];
    int i = blockIdx.x * 1024 + threadIdx.x;
    int v = (i < NN) ? hist[i] : 0;
    sc[threadIdx.x] = v;
    __syncthreads();
    for (int d = 1; d < 1024; d <<= 1) {
        int t = (threadIdx.x >= d) ? sc[threadIdx.x - d] : 0;
        __syncthreads();
        sc[threadIdx.x] += t;
        __syncthreads();
    }
    if (i < NN) {
        int excl = bbase[blockIdx.x] + sc[threadIdx.x] - v;
        offs[i] = excl;
        cursor[i] = excl;
        if (i == NN - 1) offs[NN] = excl + v;
    }
}

// packed edge record: .x = src, .y = bitcast(norm). ONE scattered 8 B store
// per edge (was two scattered 4 B stores to two arrays -> 2 lines touched).
__global__ void fill_kernel(const int* __restrict__ src, const int* __restrict__ dst,
        const float* __restrict__ dinv, int* __restrict__ cursor,
        int2* __restrict__ edges) {
    int e = blockIdx.x * blockDim.x + threadIdx.x;
    if (e >= EE) return;
    int s = src[e], d = dst[e];
    int p = atomicAdd(&cursor[d], 1);
    edges[p] = make_int2(s, __float_as_int(dinv[s] * dinv[d]));
}

// ---------------- W pre-split into MFMA-fragment-ordered bf16 ----------------
// 4 weight matrices in ONE launch (64 blocks). Per matrix: entry
// e = kind*2048 + k0*512 + ct*64 + lane; entry = 8 bf16 = one b-frag quad:
// B[k0*32+(lane>>4)*8+j][ct*16+(lane&15)], j=0..7.

__global__ __launch_bounds__(256) void wsplit_kernel(const float* __restrict__ W1,
        const float* __restrict__ W2, const float* __restrict__ W3,
        const float* __restrict__ P1, short* __restrict__ Wf) {
    int g = blockIdx.x * 256 + threadIdx.x;   // 16384 entries total
    int w = g >> 12;                          // which matrix
    int e = g & 4095;
    const float* W = (w == 0) ? W1 : (w == 1) ? W2 : (w == 2) ? W3 : P1;
    int kind = e >> 11;
    int k0 = (e >> 9) & 3;
    int ct = (e >> 6) & 7;
    int l = e & 63;
    int kb = k0 * 32 + (l >> 4) * 8;
    int c = ct * 16 + (l & 15);
    short v[8];
#pragma unroll
    for (int j = 0; j < 8; ++j) {
        float wv = W[(size_t)(kb + j) * HH + c];
        ushort hi, lo;
        split2(wv, hi, lo);
        v[j] = (short)(kind ? lo : hi);
    }
    bf16x8 pack;
#pragma unroll
    for (int j = 0; j < 8; ++j) pack[j] = v[j];
    *(bf16x8*)(Wf + (size_t)g * 8) = pack;
}

// ---------------- MFMA GEMM [M,128] x [128,128] via bf16 split ----------------
// C = Ah@Wh + Ah@Wl + Al@Wh. Block: 128 rows x 128 cols, 4 waves; wave = 32
// rows x 128 cols = 2x8 16x16 tiles. Fragment layouts per m89/m91 (verified).

__global__ __launch_bounds__(256) void gemm_mfma(const float* __restrict__ A,
        const short* __restrict__ Wf, const float* __restrict__ bias,
        float* __restrict__ C, int M, int relu) {
    __shared__ short Ah[128 * LDA];
    __shared__ short Al[128 * LDA];
    const int tid = threadIdx.x;
    const int row0 = blockIdx.x * 128;

    const float4* A4 = (const float4*)A;
#pragma unroll
    for (int i = 0; i < 16; ++i) {
        int p = i * 256 + tid;
        int row = p >> 5, k4 = p & 31;
        int gr = row0 + row;
        float4 v = make_float4(0.f, 0.f, 0.f, 0.f);
        if (gr < M) v = A4[(size_t)gr * 32 + k4];
        ushort h0, l0, h1, l1, h2, l2, h3, l3;
        split2(v.x, h0, l0); split2(v.y, h1, l1);
        split2(v.z, h2, l2); split2(v.w, h3, l3);
        *(short4*)&Ah[row * LDA + k4 * 4] =
            make_short4((short)h0, (short)h1, (short)h2, (short)h3);
        *(short4*)&Al[row * LDA + k4 * 4] =
            make_short4((short)l0, (short)l1, (short)l2, (short)l3);
    }
    __syncthreads();

    const int lane = tid & 63;
    const int wave = tid >> 6;
    const int wr0 = wave * 32;
    const int arow = lane & 15;
    const int koff = (lane >> 4) * 8;

    f32x4 acc[2][8];
#pragma unroll
    for (int rt = 0; rt < 2; ++rt)
#pragma unroll
        for (int ct = 0; ct < 8; ++ct)
#pragma unroll
            for (int m = 0; m < 4; ++m) acc[rt][ct][m] = 0.f;

    for (int k0 = 0; k0 < 4; ++k0) {
        bf16x8 wh[8], wl[8];
#pragma unroll
        for (int ct = 0; ct < 8; ++ct) {
            wh[ct] = *(const bf16x8*)(Wf + ((size_t)(k0 * 8 + ct) * 64 + lane) * 8);
            wl[ct] = *(const bf16x8*)(Wf + ((size_t)(2048 + k0 * 512 + ct * 64 + lane)) * 8);
        }
        bf16x8 ah[2], al[2];
#pragma unroll
        for (int rt = 0; rt < 2; ++rt) {
            int r = wr0 + rt * 16 + arow;
            ah[rt] = *(const bf16x8*)&Ah[r * LDA + k0 * 32 + koff];
            al[rt] = *(const bf16x8*)&Al[r * LDA + k0 * 32 + koff];
        }
#pragma unroll
        for (int rt = 0; rt < 2; ++rt)
#pragma unroll
            for (int ct = 0; ct < 8; ++ct) {
                acc[rt][ct] = __builtin_amdgcn_mfma_f32_16x16x32_bf16(
                    ah[rt], wh[ct], acc[rt][ct], 0, 0, 0);
                acc[rt][ct] = __builtin_amdgcn_mfma_f32_16x16x32_bf16(
                    ah[rt], wl[ct], acc[rt][ct], 0, 0, 0);
                acc[rt][ct] = __builtin_amdgcn_mfma_f32_16x16x32_bf16(
                    al[rt], wh[ct], acc[rt][ct], 0, 0, 0);
            }
    }

    const int ccol = lane & 15;
    const int crow = (lane >> 4) * 4;
#pragma unroll
    for (int ct = 0; ct < 8; ++ct) {
        float bv = bias ? bias[ct * 16 + ccol] : 0.f;
#pragma unroll
        for (int rt = 0; rt < 2; ++rt) {
#pragma unroll
            for (int m = 0; m < 4; ++m) {
                int gr = row0 + wr0 + rt * 16 + crow + m;
                if (gr < M) {
                    float v = acc[rt][ct][m] + bv;
                    if (relu) v = fmaxf(v, 0.f);
                    C[(size_t)gr * HH + ct * 16 + ccol] = v;
                }
            }
        }
    }
}

// ---------------- aggregation (parked at its ~3.9 TB/s gather wall) ----------------

__global__ __launch_bounds__(256) void agg_kernel(const float* __restrict__ t,
        float* __restrict__ out, const int* __restrict__ offs,
        const int2* __restrict__ edges,
        const float* __restrict__ dinv, const float* __restrict__ bias, int relu) {
    const int wave = threadIdx.x >> 6;
    const int lane = threadIdx.x & 63;
    const int node = blockIdx.x * 4 + wave;
    if (node >= NN) return;
    const int half = lane >> 5;
    const int hl = lane & 31;

    const float4* t4 = (const float4*)t;
    float ax = 0.f, ay = 0.f, az = 0.f, aw = 0.f;

    if (half == 0) {
        float di = dinv[node];
        float s = di * di;
        float4 sv = t4[(size_t)node * 32 + hl];
        ax = sv.x * s; ay = sv.y * s; az = sv.z * s; aw = sv.w * s;
    }

    int e = offs[node];
    const int e1 = offs[node + 1];
    for (; e + 8 <= e1; e += 8) {
        int2 p0 = edges[e + half],     p1 = edges[e + 2 + half];
        int2 p2 = edges[e + 4 + half], p3 = edges[e + 6 + half];
        float n0 = __int_as_float(p0.y), n1 = __int_as_float(p1.y);
        float n2 = __int_as_float(p2.y), n3 = __int_as_float(p3.y);
        float4 v0 = t4[(size_t)p0.x * 32 + hl];
        float4 v1 = t4[(size_t)p1.x * 32 + hl];
        float4 v2 = t4[(size_t)p2.x * 32 + hl];
        float4 v3 = t4[(size_t)p3.x * 32 + hl];
        ax += v0.x * n0; ay += v0.y * n0; az += v0.z * n0; aw += v0.w * n0;
        ax += v1.x * n1; ay += v1.y * n1; az += v1.z * n1; aw += v1.w * n1;
        ax += v2.x * n2; ay += v2.y * n2; az += v2.z * n2; aw += v2.w * n2;
        ax += v3.x * n3; ay += v3.y * n3; az += v3.z * n3; aw += v3.w * n3;
    }
    for (; e + 2 <= e1; e += 2) {
        int2 p = edges[e + half];
        float nm = __int_as_float(p.y);
        float4 v = t4[(size_t)p.x * 32 + hl];
        ax += v.x * nm; ay += v.y * nm; az += v.z * nm; aw += v.w * nm;
    }
    if (e < e1 && half == 0) {
        int2 p = edges[e];
        float nm = __int_as_float(p.y);
        float4 v = t4[(size_t)p.x * 32 + hl];
        ax += v.x * nm; ay += v.y * nm; az += v.z * nm; aw += v.w * nm;
    }

    ax += __shfl_xor(ax, 32); ay += __shfl_xor(ay, 32);
    az += __shfl_xor(az, 32); aw += __shfl_xor(aw, 32);

    if (half == 0) {
        if (bias) {
            float4 b = ((const float4*)bias)[hl];
            ax += b.x; ay += b.y; az += b.z; aw += b.w;
        }
        if (relu) {
            ax = fmaxf(ax, 0.f); ay = fmaxf(ay, 0.f);
            az = fmaxf(az, 0.f); aw = fmaxf(aw, 0.f);
        }
        ((float4*)out)[(size_t)node * 32 + hl] = make_float4(ax, ay, az, aw);
    }
}

// ---------------- link head ----------------

__global__ __launch_bounds__(256) void link_kernel(const float* __restrict__ h,
        const int* __restrict__ roots, float* __restrict__ linkb) {
    const int wave = threadIdx.x >> 6;
    const int lane = threadIdx.x & 63;
    const int b = blockIdx.x * 4 + wave;
    if (b >= BB) return;
    const int f = lane * 2;
    int r0 = roots[b * 2], r1 = roots[b * 2 + 1];
    float2 u = *(const float2*)&h[(size_t)r0 * HH + f];
    float2 v = *(const float2*)&h[(size_t)r1 * HH + f];
    *(float2*)&linkb[(size_t)b * HH + f] = make_float2(u.x * v.x, u.y * v.y);
}

__global__ __launch_bounds__(256) void logits_kernel(const float* __restrict__ g,
        const float* __restrict__ P2, const float* __restrict__ pb2,
        float* __restrict__ out) {
    const int wave = threadIdx.x >> 6;
    const int lane = threadIdx.x & 63;
    const int b = blockIdx.x * 4 + wave;
    if (b >= BB) return;
    const int f = lane * 2;
    float2 gv = *(const float2*)&g[(size_t)b * HH + f];
    float2 pv = *(const float2*)&P2[f];
    float s = gv.x * pv.x + gv.y * pv.y;
    for (int off = 32; off > 0; off >>= 1) s += __shfl_down(s, off);
    if (lane == 0) out[b] = s + pb2[0];
}

// ---------------- launcher ----------------

extern "C" void kernel_launch(void* const* d_in, const int* in_sizes, int n_in,
                              void* d_out, int out_size, void* d_ws, size_t ws_size,
                              hipStream_t stream) {
    const float* x   = (const float*)d_in[0];
    const int*   ei  = (const int*)d_in[1];
    const int* roots = (const int*)d_in[2];
    const float* W1  = (const float*)d_in[3];
    const float* b1  = (const float*)d_in[4];
    const float* W2  = (const float*)d_in[5];
    const float* b2  = (const float*)d_in[6];
    const float* W3  = (const float*)d_in[7];
    const float* b3  = (const float*)d_in[8];
    const float* P1  = (const float*)d_in[9];
    const float* pb1 = (const float*)d_in[10];
    const float* P2  = (const float*)d_in[11];
    const float* pb2 = (const float*)d_in[12];
    float* out = (float*)d_out;
    (void)in_sizes; (void)n_in; (void)out_size; (void)ws_size;

    char* ws = (char*)d_ws;
    size_t woff = 0;
    auto alloc = [&](size_t bytes) {
        void* p = ws + woff;
        woff += (bytes + 255) & ~(size_t)255;
        return p;
    };
    int*   hist   = (int*)  alloc((size_t)NN * 4);
    float* dinv   = (float*)alloc((size_t)NN * 4);
    int*   offs   = (int*)  alloc((size_t)(NN + 1) * 4);
    int*   cursor = (int*)  alloc((size_t)NN * 4);
    int*   bsum   = (int*)  alloc((size_t)(SCAN_NBLK + 1) * 4);
    int*   bbase  = (int*)  alloc((size_t)(SCAN_NBLK + 1) * 4);
    int2*  edges  = (int2*) alloc((size_t)EE * 8);
    float* bufA   = (float*)alloc((size_t)NN * HH * 4);
    float* bufB   = (float*)alloc((size_t)NN * HH * 4);
    float* linkb  = (float*)alloc((size_t)BB * HH * 4);
    float* gout   = (float*)alloc((size_t)BB * HH * 4);
    short* Wf     = (short*)alloc((size_t)4 * 4096 * 8 * 2);  // 4 matrices

    const int* e_src = ei;        // edge_index[0]
    const int* e_dst = ei + EE;   // edge_index[1]

    hipMemsetAsync(hist, 0, (size_t)NN * 4, stream);
    hist_kernel<<<(EE + 255) / 256, 256, 0, stream>>>(e_dst, hist);
    dinv_kernel<<<(NN + 255) / 256, 256, 0, stream>>>(hist, dinv);
    scan_partial_kernel<<<SCAN_NBLK, 1024, 0, stream>>>(hist, bsum);
    scan_sums_kernel<<<1, 128, 0, stream>>>(bsum, bbase);
    scan_offs_kernel<<<SCAN_NBLK, 1024, 0, stream>>>(hist, bbase, offs, cursor);
    fill_kernel<<<(EE + 255) / 256, 256, 0, stream>>>(e_src, e_dst, dinv, cursor, edges);

    // pre-split all 4 weight matrices (one launch)
    wsplit_kernel<<<64, 256, 0, stream>>>(W1, W2, W3, P1, Wf);
    short* Wf1 = Wf, *Wf2 = Wf + 32768, *Wf3 = Wf + 65536, *WfP1 = Wf + 98304;

    // layer 1
    gemm_mfma<<<(NN + 127) / 128, 256, 0, stream>>>(x, Wf1, nullptr, bufA, NN, 0);
    agg_kernel<<<(NN + 3) / 4, 256, 0, stream>>>(bufA, bufB, offs, edges, dinv, b1, 1);
    // layer 2
    gemm_mfma<<<(NN + 127) / 128, 256, 0, stream>>>(bufB, Wf2, nullptr, bufA, NN, 0);
    agg_kernel<<<(NN + 3) / 4, 256, 0, stream>>>(bufA, bufB, offs, edges, dinv, b2, 1);
    // layer 3 (no relu)
    gemm_mfma<<<(NN + 127) / 128, 256, 0, stream>>>(bufB, Wf3, nullptr, bufA, NN, 0);
    agg_kernel<<<(NN + 3) / 4, 256, 0, stream>>>(bufA, bufB, offs, edges, dinv, b3, 0);

    // head
    link_kernel<<<(BB + 3) / 4, 256, 0, stream>>>(bufB, roots, linkb);
    gemm_mfma<<<(BB + 127) / 128, 256, 0, stream>>>(linkb, WfP1, pb1, gout, BB, 1);
    logits_kernel<<<(BB + 3) / 4, 256, 0, stream>>>(gout, P2, pb2, out);
}

// Round 14
// 738.685 us; speedup vs baseline: 1.2132x; 1.0403x over previous
//
#include <hip/hip_runtime.h>

#define NN 100000
#define EE 1600000
#define HH 128
#define BB 8192
#define SCAN_NBLK ((NN + 1023) / 1024)   // 98

typedef __attribute__((ext_vector_type(8))) short bf16x8;
typedef __attribute__((ext_vector_type(4))) float f32x4;

// split fp32 into bf16 hi + bf16 lo (truncation; dropped al*wl <= 2^-16 rel)
__device__ __forceinline__ void split2(float a, ushort& hi, ushort& lo) {
    unsigned u = __float_as_uint(a);
    hi = (ushort)(u >> 16);
    float hf = __uint_as_float(u & 0xFFFF0000u);
    float l = a - hf;
    lo = (ushort)(__float_as_uint(l) >> 16);
}

// ---------------- CSR build ----------------

__global__ void hist_kernel(const int* __restrict__ dst, int* __restrict__ hist) {
    int e = blockIdx.x * blockDim.x + threadIdx.x;
    if (e < EE) atomicAdd(&hist[dst[e]], 1);
}

__global__ void dinv_kernel(const int* __restrict__ hist, float* __restrict__ dinv) {
    int i = blockIdx.x * blockDim.x + threadIdx.x;
    if (i < NN) dinv[i] = rsqrtf((float)hist[i] + 1.0f);
}

__global__ __launch_bounds__(1024) void scan_partial_kernel(const int* __restrict__ hist,
        int* __restrict__ bsum) {
    __shared__ int red[1024];
    int i = blockIdx.x * 1024 + threadIdx.x;
    int v = (i < NN) ? hist[i] : 0;
    red[threadIdx.x] = v;
    __syncthreads();
    for (int d = 512; d > 0; d >>= 1) {
        if (threadIdx.x < d) red[threadIdx.x] += red[threadIdx.x + d];
        __syncthreads();
    }
    if (threadIdx.x == 0) bsum[blockIdx.x] = red[0];
}

__global__ __launch_bounds__(128) void scan_sums_kernel(const int* __restrict__ bsum,
        int* __restrict__ bbase) {
    __shared__ int sc[128];
    int t = threadIdx.x;
    int v = (t < SCAN_NBLK) ? bsum[t] : 0;
    sc[t] = v;
    __syncthreads();
    for (int d = 1; d < 128; d <<= 1) {
        int u = (t >= d) ? sc[t - d] : 0;
        __syncthreads();
        sc[t] += u;
        __syncthreads();
    }
    if (t <= SCAN_NBLK) bbase[t] = sc[t] - v;
}

__global__ __launch_bounds__(1024) void scan_offs_kernel(const int* __restrict__ hist,
        const int* __restrict__ bbase, int* __restrict__ offs, int* __restrict__ cursor) {
    __shared__ int sc[1024];
    int i = blockIdx.x * 1024 + threadIdx.x;
    int v = (i < NN) ? hist[i] : 0;
    sc[threadIdx.x] = v;
    __syncthreads();
    for (int d = 1; d < 1024; d <<= 1) {
        int t = (threadIdx.x >= d) ? sc[threadIdx.x - d] : 0;
        __syncthreads();
        sc[threadIdx.x] += t;
        __syncthreads();
    }
    if (i < NN) {
        int excl = bbase[blockIdx.x] + sc[threadIdx.x] - v;
        offs[i] = excl;
        cursor[i] = excl;
        if (i == NN - 1) offs[NN] = excl + v;
    }
}

__global__ void fill_kernel(const int* __restrict__ src, const int* __restrict__ dst,
        const float* __restrict__ dinv, int* __restrict__ cursor,
        int2* __restrict__ edges) {
    int e = blockIdx.x * blockDim.x + threadIdx.x;
    if (e >= EE) return;
    int s = src[e], d = dst[e];
    int p = atomicAdd(&cursor[d], 1);
    edges[p] = make_int2(s, __float_as_int(dinv[s] * dinv[d]));
}

// ---------------- W pre-split into MFMA-fragment-ordered bf16 ----------------

__global__ __launch_bounds__(256) void wsplit_kernel(const float* __restrict__ W1,
        const float* __restrict__ W2, const float* __restrict__ W3,
        const float* __restrict__ P1, short* __restrict__ Wf) {
    int g = blockIdx.x * 256 + threadIdx.x;   // 16384 entries total
    int w = g >> 12;
    int e = g & 4095;
    const float* W = (w == 0) ? W1 : (w == 1) ? W2 : (w == 2) ? W3 : P1;
    int kind = e >> 11;
    int k0 = (e >> 9) & 3;
    int ct = (e >> 6) & 7;
    int l = e & 63;
    int kb = k0 * 32 + (l >> 4) * 8;
    int c = ct * 16 + (l & 15);
    short v[8];
#pragma unroll
    for (int j = 0; j < 8; ++j) {
        float wv = W[(size_t)(kb + j) * HH + c];
        ushort hi, lo;
        split2(wv, hi, lo);
        v[j] = (short)(kind ? lo : hi);
    }
    bf16x8 pack;
#pragma unroll
    for (int j = 0; j < 8; ++j) pack[j] = v[j];
    *(bf16x8*)(Wf + (size_t)g * 8) = pack;
}

// ---------------- MFMA GEMM v2: no LDS, direct-from-global fragments --------
// v1 was ~100 us (5x roofline): 68 KB LDS -> 2 waves/SIMD, serialized L2
// W-frag loads with nothing to hide behind, full staging pass + barrier.
// v2: each lane builds its A-fragments (row=lane&15, k=(lane>>4)*8+j) by
// reading two float4 of its own row per (rt,k0) and splitting in registers.
// Same global traffic (tile read exactly once), zero LDS, zero barriers,
// higher occupancy -> W-load latency hidden by MFMA of other waves.

__global__ __launch_bounds__(256) void gemm_mfma(const float* __restrict__ A,
        const short* __restrict__ Wf, const float* __restrict__ bias,
        float* __restrict__ C, int M, int relu) {
    const int tid = threadIdx.x;
    const int row0 = blockIdx.x * 128;
    const int lane = tid & 63;
    const int wave = tid >> 6;
    const int wr0 = wave * 32;
    const int arow = lane & 15;
    const int koff = (lane >> 4) * 8;

    f32x4 acc[2][8];
#pragma unroll
    for (int rt = 0; rt < 2; ++rt)
#pragma unroll
        for (int ct = 0; ct < 8; ++ct)
#pragma unroll
            for (int m = 0; m < 4; ++m) acc[rt][ct][m] = 0.f;

    for (int k0 = 0; k0 < 4; ++k0) {
        const int kb = k0 * 32 + koff;
        bf16x8 wh[8], wl[8];
#pragma unroll
        for (int ct = 0; ct < 8; ++ct) {
            wh[ct] = *(const bf16x8*)(Wf + ((size_t)(k0 * 8 + ct) * 64 + lane) * 8);
            wl[ct] = *(const bf16x8*)(Wf + ((size_t)(2048 + k0 * 512 + ct * 64 + lane)) * 8);
        }
        bf16x8 ah[2], al[2];
#pragma unroll
        for (int rt = 0; rt < 2; ++rt) {
            int gr = row0 + wr0 + rt * 16 + arow;
            float4 a0 = make_float4(0.f, 0.f, 0.f, 0.f);
            float4 a1 = make_float4(0.f, 0.f, 0.f, 0.f);
            if (gr < M) {
                a0 = *(const float4*)&A[(size_t)gr * HH + kb];
                a1 = *(const float4*)&A[(size_t)gr * HH + kb + 4];
            }
            ushort h, l;
            split2(a0.x, h, l); ah[rt][0] = (short)h; al[rt][0] = (short)l;
            split2(a0.y, h, l); ah[rt][1] = (short)h; al[rt][1] = (short)l;
            split2(a0.z, h, l); ah[rt][2] = (short)h; al[rt][2] = (short)l;
            split2(a0.w, h, l); ah[rt][3] = (short)h; al[rt][3] = (short)l;
            split2(a1.x, h, l); ah[rt][4] = (short)h; al[rt][4] = (short)l;
            split2(a1.y, h, l); ah[rt][5] = (short)h; al[rt][5] = (short)l;
            split2(a1.z, h, l); ah[rt][6] = (short)h; al[rt][6] = (short)l;
            split2(a1.w, h, l); ah[rt][7] = (short)h; al[rt][7] = (short)l;
        }
#pragma unroll
        for (int rt = 0; rt < 2; ++rt)
#pragma unroll
            for (int ct = 0; ct < 8; ++ct) {
                acc[rt][ct] = __builtin_amdgcn_mfma_f32_16x16x32_bf16(
                    ah[rt], wh[ct], acc[rt][ct], 0, 0, 0);
                acc[rt][ct] = __builtin_amdgcn_mfma_f32_16x16x32_bf16(
                    ah[rt], wl[ct], acc[rt][ct], 0, 0, 0);
                acc[rt][ct] = __builtin_amdgcn_mfma_f32_16x16x32_bf16(
                    al[rt], wh[ct], acc[rt][ct], 0, 0, 0);
            }
    }

    const int ccol = lane & 15;
    const int crow = (lane >> 4) * 4;
#pragma unroll
    for (int ct = 0; ct < 8; ++ct) {
        float bv = bias ? bias[ct * 16 + ccol] : 0.f;
#pragma unroll
        for (int rt = 0; rt < 2; ++rt) {
#pragma unroll
            for (int m = 0; m < 4; ++m) {
                int gr = row0 + wr0 + rt * 16 + crow + m;
                if (gr < M) {
                    float v = acc[rt][ct][m] + bv;
                    if (relu) v = fmaxf(v, 0.f);
                    C[(size_t)gr * HH + ct * 16 + ccol] = v;
                }
            }
        }
    }
}

// ---------------- aggregation (parked at its ~3.9 TB/s gather wall) ----------------

__global__ __launch_bounds__(256) void agg_kernel(const float* __restrict__ t,
        float* __restrict__ out, const int* __restrict__ offs,
        const int2* __restrict__ edges,
        const float* __restrict__ dinv, const float* __restrict__ bias, int relu) {
    const int wave = threadIdx.x >> 6;
    const int lane = threadIdx.x & 63;
    const int node = blockIdx.x * 4 + wave;
    if (node >= NN) return;
    const int half = lane >> 5;
    const int hl = lane & 31;

    const float4* t4 = (const float4*)t;
    float ax = 0.f, ay = 0.f, az = 0.f, aw = 0.f;

    if (half == 0) {
        float di = dinv[node];
        float s = di * di;
        float4 sv = t4[(size_t)node * 32 + hl];
        ax = sv.x * s; ay = sv.y * s; az = sv.z * s; aw = sv.w * s;
    }

    int e = offs[node];
    const int e1 = offs[node + 1];
    for (; e + 8 <= e1; e += 8) {
        int2 p0 = edges[e + half],     p1 = edges[e + 2 + half];
        int2 p2 = edges[e + 4 + half], p3 = edges[e + 6 + half];
        float n0 = __int_as_float(p0.y), n1 = __int_as_float(p1.y);
        float n2 = __int_as_float(p2.y), n3 = __int_as_float(p3.y);
        float4 v0 = t4[(size_t)p0.x * 32 + hl];
        float4 v1 = t4[(size_t)p1.x * 32 + hl];
        float4 v2 = t4[(size_t)p2.x * 32 + hl];
        float4 v3 = t4[(size_t)p3.x * 32 + hl];
        ax += v0.x * n0; ay += v0.y * n0; az += v0.z * n0; aw += v0.w * n0;
        ax += v1.x * n1; ay += v1.y * n1; az += v1.z * n1; aw += v1.w * n1;
        ax += v2.x * n2; ay += v2.y * n2; az += v2.z * n2; aw += v2.w * n2;
        ax += v3.x * n3; ay += v3.y * n3; az += v3.z * n3; aw += v3.w * n3;
    }
    for (; e + 2 <= e1; e += 2) {
        int2 p = edges[e + half];
        float nm = __int_as_float(p.y);
        float4 v = t4[(size_t)p.x * 32 + hl];
        ax += v.x * nm; ay += v.y * nm; az += v.z * nm; aw += v.w * nm;
    }
    if (e < e1 && half == 0) {
        int2 p = edges[e];
        float nm = __int_as_float(p.y);
        float4 v = t4[(size_t)p.x * 32 + hl];
        ax += v.x * nm; ay += v.y * nm; az += v.z * nm; aw += v.w * nm;
    }

    ax += __shfl_xor(ax, 32); ay += __shfl_xor(ay, 32);
    az += __shfl_xor(az, 32); aw += __shfl_xor(aw, 32);

    if (half == 0) {
        if (bias) {
            float4 b = ((const float4*)bias)[hl];
            ax += b.x; ay += b.y; az += b.z; aw += b.w;
        }
        if (relu) {
            ax = fmaxf(ax, 0.f); ay = fmaxf(ay, 0.f);
            az = fmaxf(az, 0.f); aw = fmaxf(aw, 0.f);
        }
        ((float4*)out)[(size_t)node * 32 + hl] = make_float4(ax, ay, az, aw);
    }
}

// ---------------- link head ----------------

__global__ __launch_bounds__(256) void link_kernel(const float* __restrict__ h,
        const int* __restrict__ roots, float* __restrict__ linkb) {
    const int wave = threadIdx.x >> 6;
    const int lane = threadIdx.x & 63;
    const int b = blockIdx.x * 4 + wave;
    if (b >= BB) return;
    const int f = lane * 2;
    int r0 = roots[b * 2], r1 = roots[b * 2 + 1];
    float2 u = *(const float2*)&h[(size_t)r0 * HH + f];
    float2 v = *(const float2*)&h[(size_t)r1 * HH + f];
    *(float2*)&linkb[(size_t)b * HH + f] = make_float2(u.x * v.x, u.y * v.y);
}

__global__ __launch_bounds__(256) void logits_kernel(const float* __restrict__ g,
        const float* __restrict__ P2, const float* __restrict__ pb2,
        float* __restrict__ out) {
    const int wave = threadIdx.x >> 6;
    const int lane = threadIdx.x & 63;
    const int b = blockIdx.x * 4 + wave;
    if (b >= BB) return;
    const int f = lane * 2;
    float2 gv = *(const float2*)&g[(size_t)b * HH + f];
    float2 pv = *(const float2*)&P2[f];
    float s = gv.x * pv.x + gv.y * pv.y;
    for (int off = 32; off > 0; off >>= 1) s += __shfl_down(s, off);
    if (lane == 0) out[b] = s + pb2[0];
}

// ---------------- launcher ----------------

extern "C" void kernel_launch(void* const* d_in, const int* in_sizes, int n_in,
                              void* d_out, int out_size, void* d_ws, size_t ws_size,
                              hipStream_t stream) {
    const float* x   = (const float*)d_in[0];
    const int*   ei  = (const int*)d_in[1];
    const int* roots = (const int*)d_in[2];
    const float* W1  = (const float*)d_in[3];
    const float* b1  = (const float*)d_in[4];
    const float* W2  = (const float*)d_in[5];
    const float* b2  = (const float*)d_in[6];
    const float* W3  = (const float*)d_in[7];
    const float* b3  = (const float*)d_in[8];
    const float* P1  = (const float*)d_in[9];
    const float* pb1 = (const float*)d_in[10];
    const float* P2  = (const float*)d_in[11];
    const float* pb2 = (const float*)d_in[12];
    float* out = (float*)d_out;
    (void)in_sizes; (void)n_in; (void)out_size; (void)ws_size;

    char* ws = (char*)d_ws;
    size_t woff = 0;
    auto alloc = [&](size_t bytes) {
        void* p = ws + woff;
        woff += (bytes + 255) & ~(size_t)255;
        return p;
    };
    int*   hist   = (int*)  alloc((size_t)NN * 4);
    float* dinv   = (float*)alloc((size_t)NN * 4);
    int*   offs   = (int*)  alloc((size_t)(NN + 1) * 4);
    int*   cursor = (int*)  alloc((size_t)NN * 4);
    int*   bsum   = (int*)  alloc((size_t)(SCAN_NBLK + 1) * 4);
    int*   bbase  = (int*)  alloc((size_t)(SCAN_NBLK + 1) * 4);
    int2*  edges  = (int2*) alloc((size_t)EE * 8);
    float* bufA   = (float*)alloc((size_t)NN * HH * 4);
    float* bufB   = (float*)alloc((size_t)NN * HH * 4);
    float* linkb  = (float*)alloc((size_t)BB * HH * 4);
    float* gout   = (float*)alloc((size_t)BB * HH * 4);
    short* Wf     = (short*)alloc((size_t)4 * 4096 * 8 * 2);  // 4 matrices

    const int* e_src = ei;        // edge_index[0]
    const int* e_dst = ei + EE;   // edge_index[1]

    hipMemsetAsync(hist, 0, (size_t)NN * 4, stream);
    hist_kernel<<<(EE + 255) / 256, 256, 0, stream>>>(e_dst, hist);
    dinv_kernel<<<(NN + 255) / 256, 256, 0, stream>>>(hist, dinv);
    scan_partial_kernel<<<SCAN_NBLK, 1024, 0, stream>>>(hist, bsum);
    scan_sums_kernel<<<1, 128, 0, stream>>>(bsum, bbase);
    scan_offs_kernel<<<SCAN_NBLK, 1024, 0, stream>>>(hist, bbase, offs, cursor);
    fill_kernel<<<(EE + 255) / 256, 256, 0, stream>>>(e_src, e_dst, dinv, cursor, edges);

    wsplit_kernel<<<64, 256, 0, stream>>>(W1, W2, W3, P1, Wf);
    short* Wf1 = Wf, *Wf2 = Wf + 32768, *Wf3 = Wf + 65536, *WfP1 = Wf + 98304;

    // layer 1
    gemm_mfma<<<(NN + 127) / 128, 256, 0, stream>>>(x, Wf1, nullptr, bufA, NN, 0);
    agg_kernel<<<(NN + 3) / 4, 256, 0, stream>>>(bufA, bufB, offs, edges, dinv, b1, 1);
    // layer 2
    gemm_mfma<<<(NN + 127) / 128, 256, 0, stream>>>(bufB, Wf2, nullptr, bufA, NN, 0);
    agg_kernel<<<(NN + 3) / 4, 256, 0, stream>>>(bufA, bufB, offs, edges, dinv, b2, 1);
    // layer 3 (no relu)
    gemm_mfma<<<(NN + 127) / 128, 256, 0, stream>>>(bufB, Wf3, nullptr, bufA, NN, 0);
    agg_kernel<<<(NN + 3) / 4, 256, 0, stream>>>(bufA, bufB, offs, edges, dinv, b3, 0);

    // head
    link_kernel<<<(BB + 3) / 4, 256, 0, stream>>>(bufB, roots, linkb);
    gemm_mfma<<<(BB + 127) / 128, 256, 0, stream>>>(linkb, WfP1, pb1, gout, BB, 1);
    logits_kernel<<<(BB + 3) / 4, 256, 0, stream>>>(gout, P2, pb2, out);
}